// Round 15
// baseline (267.934 us; speedup 1.0000x reference)
//
#include <hip/hip_runtime.h>
#include <hip/hip_bf16.h>
#include <stdint.h>

#define DEV __device__ __forceinline__

typedef unsigned short u16;
typedef unsigned int u32;
typedef __bf16 bf16x8 __attribute__((ext_vector_type(8)));
typedef float f32x4 __attribute__((ext_vector_type(4)));
typedef u16 u16x4 __attribute__((ext_vector_type(4)));
typedef u32 u32x4 __attribute__((ext_vector_type(4)));

typedef __attribute__((address_space(1))) u32 u32_as1;
typedef __attribute__((address_space(3))) u32 u32_as3;

static constexpr int Bn = 4, Tn = 2048, Dm = 2048, Hn = 16, Dh = 128;
static constexpr int BT = Bn * Tn; // 8192
static constexpr int KVSTR = 256;  // fused K|V row stride (elements)
static constexpr float CL2 = 0.1275174147f; // log2(e)/sqrt(128)

#define VMCNT(n) asm volatile("s_waitcnt vmcnt(" #n ")" ::: "memory")
#define BARRIER() __builtin_amdgcn_s_barrier()

DEV u16 f2bf(float f) {
  u32 u = __builtin_bit_cast(u32, f);
  u += 0x7fffu + ((u >> 16) & 1u);   // RNE
  return (u16)(u >> 16);
}
DEV u16 cvt_bf(float f) { return __builtin_bit_cast(u16, (__bf16)f); }
DEV u32 cvt_pk_bf16(float lo, float hi) {   // u32 = {lo_bf16, hi_bf16<<16}
  u32 r;
  asm("v_cvt_pk_bf16_f32 %0, %1, %2" : "=v"(r) : "v"(lo), "v"(hi));
  return r;
}

// async 16B global->LDS; LDS dest is wave-linear (base + lane*16), so the
// XOR swizzle is applied on the GLOBAL source side (rule #21).
DEV void gl2lds16(const void* g, void* l) {
  __builtin_amdgcn_global_load_lds((u32_as1*)(uintptr_t)g,
                                   (u32_as3*)(u32)(uintptr_t)l, 16, 0, 0);
}

// ---------------- fused prep: cast x (z=0) + 4 weight transposes (z=1..4) ----
__global__ __launch_bounds__(256) void k_prep(const float* __restrict__ x,
                                              u16* __restrict__ xb,
                                              const float* __restrict__ Wq,
                                              u16* __restrict__ Wqt,
                                              const float* __restrict__ Wo,
                                              u16* __restrict__ Wot,
                                              const float* __restrict__ Wk,
                                              const float* __restrict__ Wv,
                                              u16* __restrict__ Wkvt) {
  const int z = blockIdx.z;
  const int xx = threadIdx.x, yy = threadIdx.y; // (32,8)
  if (z == 0) {  // cast f32 -> bf16 x4: 4096 blocks x 1024 groups (exact)
    const int tid = yy * 32 + xx;
    int i = (blockIdx.y * 64 + blockIdx.x) * 1024 + tid;
#pragma unroll
    for (int k = 0; k < 4; ++k, i += 256) {
      f32x4 v = ((const f32x4*)x)[i];
      u16x4 o;
      o.x = f2bf(v.x); o.y = f2bf(v.y); o.z = f2bf(v.z); o.w = f2bf(v.w);
      ((u16x4*)xb)[i] = o;
    }
    return;
  }
  const float* in; u16* out; int R, C;
  if (z == 1)      { in = Wq; out = Wqt; R = Dm; C = Dm; }
  else if (z == 2) { in = Wo; out = Wot; R = Dm; C = Dm; }
  else if (z == 3) { in = Wk; out = Wkvt; R = Dm; C = Dh; }
  else             { in = Wv; out = Wkvt + (size_t)Dh * Dm; R = Dm; C = Dh; }
  if (blockIdx.x * 32 >= C) return;  // block-uniform early out (Dh tensors)
  __shared__ float t[32][33];
  const int r0 = blockIdx.y * 32, c0 = blockIdx.x * 32;
#pragma unroll
  for (int i = 0; i < 4; ++i)
    t[yy + i * 8][xx] = in[(size_t)(r0 + yy + i * 8) * C + c0 + xx];
  __syncthreads();
#pragma unroll
  for (int i = 0; i < 4; ++i)
    out[(size_t)(c0 + yy + i * 8) * R + r0 + xx] = f2bf(t[xx][yy + i * 8]);
}

// ---- transpose bf16 in[R][inStride] (window C) -> out[C][R], with the PV
// kv-permutation sigma applied within each 32-token column group:
// out[d][base + x] = in[base + sigma(x)][d], sigma(8g+i)=16*(i>>2)+4g+(i&3).
__global__ __launch_bounds__(256) void k_transpose_v(const u16* __restrict__ in,
                                                     int inStride,
                                                     u16* __restrict__ out,
                                                     int R, int C) {
  __shared__ u16 t[32][34];
  const int r0 = blockIdx.y * 32, c0 = blockIdx.x * 32;
  const int x = threadIdx.x, y = threadIdx.y;
#pragma unroll
  for (int i = 0; i < 4; ++i)
    t[y + i * 8][x] = in[(size_t)(r0 + y + i * 8) * inStride + c0 + x];
  __syncthreads();
  const int sx = (((x & 7) >> 2) << 4) | (((x >> 3) & 3) << 2) | (x & 3);
#pragma unroll
  for (int i = 0; i < 4; ++i)
    out[(size_t)(c0 + y + i * 8) * R + r0 + x] = t[sx][y + i * 8];
}

// ---------------- KV projection, split-K=4: partial f32 (no bias) ----------------
// Attn-style depth-1 pipeline: K+V... A+B dbuf (2x32KB), one VMCNT(0)+BARRIER
// per K-step, stage t+1 into the dead opposite buffer, reads+MFMA co-scheduled.
__global__ __launch_bounds__(256) void k_gemm_kv(const u16* __restrict__ A,
                                                 const u16* __restrict__ Bt,
                                                 float* __restrict__ P,
                                                 int M, int N, int K) {
  __shared__ __align__(1024) char smem[65536];
  const int tid = threadIdx.x;
  const int wid = tid >> 6, lane = tid & 63;
  const int g = lane >> 4, r = lane & 15;
  const int wr = wid >> 1, wc = wid & 1;
  const int m0 = blockIdx.x * 128, n0 = blockIdx.y * 128;
  const int kbase = blockIdx.z * 512;
  P += (size_t)blockIdx.z * M * N;

  auto stage = [&](int tt) {
    const int k0 = kbase + tt * 64;
    char* base = smem + ((tt & 1) << 15);
#pragma unroll
    for (int n = 0; n < 4; ++n) {
      const int L = n * 4096 + tid * 16;
      const int row = L >> 7;
      const int colb = (L & 127) ^ ((row & 7) << 4);
      gl2lds16((const char*)A + ((size_t)(m0 + row) * K + k0) * 2 + colb, base + L);
      gl2lds16((const char*)Bt + ((size_t)(n0 + row) * K + k0) * 2 + colb, base + 16384 + L);
    }
  };

  f32x4 acc[4][4];
#pragma unroll
  for (int m = 0; m < 4; ++m)
#pragma unroll
    for (int n = 0; n < 4; ++n) acc[m][n] = (f32x4)(0.f);

  stage(0);
  for (int tt = 0; tt < 8; ++tt) {
    VMCNT(0);
    BARRIER();
    const char* As = smem + ((tt & 1) << 15);
    const char* Bs = As + 16384;
    if (tt + 1 < 8) stage(tt + 1);
#pragma unroll
    for (int kk = 0; kk < 2; ++kk) {
      bf16x8 a[4], b[4];
#pragma unroll
      for (int m = 0; m < 4; ++m) {
        const int row = wr * 64 + m * 16 + r;
        a[m] = *(const bf16x8*)(As + row * 128 + ((kk * 64 + g * 16) ^ ((row & 7) << 4)));
      }
#pragma unroll
      for (int n = 0; n < 4; ++n) {
        const int row = wc * 64 + n * 16 + r;
        b[n] = *(const bf16x8*)(Bs + row * 128 + ((kk * 64 + g * 16) ^ ((row & 7) << 4)));
      }
      __builtin_amdgcn_s_setprio(1);
#pragma unroll
      for (int m = 0; m < 4; ++m)
#pragma unroll
        for (int n = 0; n < 4; ++n)
          acc[m][n] = __builtin_amdgcn_mfma_f32_16x16x32_bf16(a[m], b[n], acc[m][n], 0, 0, 0);
      __builtin_amdgcn_s_setprio(0);
    }
  }

#pragma unroll
  for (int n = 0; n < 4; ++n) {
    const int col = n0 + wc * 64 + n * 16 + r;
#pragma unroll
    for (int m = 0; m < 4; ++m)
#pragma unroll
      for (int j = 0; j < 4; ++j) {
        const int grow = m0 + wr * 64 + m * 16 + 4 * g + j;
        P[(size_t)grow * N + col] = acc[m][n][j];
      }
  }
}

// ---------------- KV reduce: sum 4 partials + bias -> bf16 KV ----------------
__global__ __launch_bounds__(256) void k_kv_reduce(const float* __restrict__ P,
                                                   const float* __restrict__ bk,
                                                   const float* __restrict__ bv,
                                                   u16* __restrict__ KV) {
  const int i = blockIdx.x * 256 + threadIdx.x;     // f32x4 group index
  const size_t S = (size_t)BT * KVSTR / 4;          // groups per slice
  f32x4 s0 = ((const f32x4*)P)[i];
  f32x4 s1 = ((const f32x4*)P)[i + S];
  f32x4 s2 = ((const f32x4*)P)[i + 2 * S];
  f32x4 s3 = ((const f32x4*)P)[i + 3 * S];
  const int col = (i * 4) & (KVSTR - 1);
  u16x4 o;
#pragma unroll
  for (int j = 0; j < 4; ++j) {
    const int c = col + j;
    const float b = (c < Dh) ? bk[c] : bv[c - Dh];
    o[j] = cvt_bf((s0[j] + s1[j]) + (s2[j] + s3[j]) + b);
  }
  ((u16x4*)KV)[i] = o;
}

// ---------------- GEMM 256x256, 8-wave, attn-style depth-1 pipeline ----------
// One VMCNT(0)+BARRIER per K-tile; stage t+1 into the dead opposite buffer
// right after the barrier; all 24 ds_read_b128 + 64 MFMA in one window so the
// compiler's fine-grained lgkmcnt interleaves DS and MFMA (the 4-phase version
// alternated DS-only and MFMA-only windows). Quadrant order Q00,Q01,Q11,Q10
// bounds fragment liveness (~210 VGPR, no spill at 2 waves/SIMD).
template <typename OutT>
__global__ __launch_bounds__(512, 2) void k_gemm256(const u16* __restrict__ A,
                                                    const u16* __restrict__ Bt,
                                                    const float* __restrict__ bias,
                                                    OutT* __restrict__ C,
                                                    int M, int N, int K,
                                                    float oscale) {
  extern __shared__ char smem[];
  const int tid = threadIdx.x;
  const int wid = tid >> 6, lane = tid & 63;
  const int g = lane >> 4, r = lane & 15;
  const int wm = wid >> 2, wn = wid & 3;

  const int nbn = N >> 8;
  const int cpx = gridDim.x >> 3;
  const int linear = (blockIdx.x & 7) * cpx + (blockIdx.x >> 3);
  const int m0 = (linear / nbn) << 8;
  const int n0 = (linear % nbn) << 8;

  const int rowInCh = lane >> 3;
  const int colb = ((lane & 7) << 4) ^ (rowInCh << 4);
  const char* srcA0; const char* srcA1; const char* srcA2; const char* srcA3;
  const char* srcB0; const char* srcB1; const char* srcB2; const char* srcB3;
  int ldsA[4], ldsB[4];
  {
    const int wnh = (wid >> 1) & 1;
    const int cbb = ((wid >> 2) << 1) | (wid & 1);
    const char* sa[4]; const char* sb[4];
#pragma unroll
    for (int i = 0; i < 4; ++i) {
      const int chA = ((wid & 3) << 2) + i;
      const int lrA = (wm << 7) + (chA << 3) + rowInCh;
      sa[i] = (const char*)A + ((size_t)(m0 + lrA) * K) * 2 + colb;
      ldsA[i] = ((wm << 7) + (chA << 3)) * 128 + lane * 16;
      const int chB = (cbb << 2) + i;
      const int lrB = (wnh << 7) + (chB << 3) + rowInCh;
      sb[i] = (const char*)Bt + ((size_t)(n0 + lrB) * K) * 2 + colb;
      ldsB[i] = 32768 + ((wnh << 7) + (chB << 3)) * 128 + lane * 16;
    }
    srcA0 = sa[0]; srcA1 = sa[1]; srcA2 = sa[2]; srcA3 = sa[3];
    srcB0 = sb[0]; srcB1 = sb[1]; srcB2 = sb[2]; srcB3 = sb[3];
  }

  auto stage = [&](int t) {
    const size_t ko = (size_t)t * 128;
    char* base = smem + ((t & 1) << 16);
    gl2lds16(srcA0 + ko, base + ldsA[0]);
    gl2lds16(srcA1 + ko, base + ldsA[1]);
    gl2lds16(srcA2 + ko, base + ldsA[2]);
    gl2lds16(srcA3 + ko, base + ldsA[3]);
    gl2lds16(srcB0 + ko, base + ldsB[0]);
    gl2lds16(srcB1 + ko, base + ldsB[1]);
    gl2lds16(srcB2 + ko, base + ldsB[2]);
    gl2lds16(srcB3 + ko, base + ldsB[3]);
  };

  f32x4 acc[8][4];
#pragma unroll
  for (int m = 0; m < 8; ++m)
#pragma unroll
    for (int n = 0; n < 4; ++n) acc[m][n] = (f32x4)(0.f);

  auto readA = [&](const char* Ab, int qm, bf16x8 (&a)[8]) {
#pragma unroll
    for (int m = 0; m < 4; ++m) {
      const int row = (wm << 7) + ((qm * 4 + m) << 4) + r;
#pragma unroll
      for (int kk = 0; kk < 2; ++kk)
        a[m * 2 + kk] = *(const bf16x8*)(Ab + row * 128 + ((kk * 64 + g * 16) ^ ((row & 7) << 4)));
    }
  };
  auto readB = [&](const char* Bb, int qn, bf16x8 (&b)[4]) {
#pragma unroll
    for (int n = 0; n < 2; ++n) {
      const int row = (wn << 6) + ((qn * 2 + n) << 4) + r;
#pragma unroll
      for (int kk = 0; kk < 2; ++kk)
        b[n * 2 + kk] = *(const bf16x8*)(Bb + row * 128 + ((kk * 64 + g * 16) ^ ((row & 7) << 4)));
    }
  };
  auto mfmaQ = [&](const bf16x8 (&a)[8], const bf16x8 (&b)[4], int qm, int qn) {
    __builtin_amdgcn_s_setprio(1);
#pragma unroll
    for (int m = 0; m < 4; ++m)
#pragma unroll
      for (int n = 0; n < 2; ++n)
#pragma unroll
        for (int kk = 0; kk < 2; ++kk)
          acc[qm * 4 + m][qn * 2 + n] = __builtin_amdgcn_mfma_f32_16x16x32_bf16(
              a[m * 2 + kk], b[n * 2 + kk], acc[qm * 4 + m][qn * 2 + n], 0, 0, 0);
    __builtin_amdgcn_s_setprio(0);
  };

  const int NT = K >> 6;
  stage(0);

  bf16x8 a0[8], a1[8], b0[4], b1[4];
  for (int t = 0; t < NT; ++t) {
    VMCNT(0);    // this wave's stage(t) loads landed
    BARRIER();   // all waves' parts landed; buffer (t+1)&1 dead
    const char* Ab = smem + ((t & 1) << 16);
    const char* Bb = Ab + 32768;
    if (t + 1 < NT) stage(t + 1);
    readA(Ab, 0, a0);
    readB(Bb, 0, b0);
    mfmaQ(a0, b0, 0, 0);
    readB(Bb, 1, b1);
    mfmaQ(a0, b1, 0, 1);
    readA(Ab, 1, a1);
    mfmaQ(a1, b1, 1, 1);
    mfmaQ(a1, b0, 1, 0);
  }

#pragma unroll
  for (int n = 0; n < 4; ++n) {
    const int col = n0 + wn * 64 + n * 16 + r;
    const float bv = bias[col];
#pragma unroll
    for (int m = 0; m < 8; ++m) {
#pragma unroll
      for (int j = 0; j < 4; ++j) {
        const int grow = m0 + wm * 128 + m * 16 + 4 * g + j;
        const float v = (acc[m][n][j] + bv) * oscale;
        if constexpr (sizeof(OutT) == 2)
          ((u16*)C)[(size_t)grow * N + col] = cvt_bf(v);
        else
          ((float*)C)[(size_t)grow * N + col] = v;
      }
    }
  }
}

// ---------------- flash attention (MQA), causal, SWAPPED QK^T ----------------
// R13 best (83us): 512 uniform paired blocks, 4 waves x 32 q-rows, 2 blocks/CU,
// K+V dbuf, one VMCNT(0)+BARRIER per tile, FIXED-MAX softmax (FM=16).
__global__ __launch_bounds__(256, 2) void k_attn(const u16* __restrict__ Q,
                                                 const u16* __restrict__ Kb,
                                                 const u16* __restrict__ VT,
                                                 u16* __restrict__ O) {
  __shared__ __align__(1024) char smem[65536];
  // K dbuf: smem + (cur<<14)          (2 x 16KB, [64 kv][256B] swizzled)
  // V dbuf: smem + 32768 + (cur<<14)  (2 x 16KB, [128 d][128B kv] swz+perm)

  const int tid = threadIdx.x;
  const int wq = tid >> 6, lane = tid & 63;
  const int g = lane >> 4, r = lane & 15;

  const int bid = blockIdx.x;                // 512
  const int xcd = bid & 7, ii = bid >> 3;    // ii 0..63
  const int b = xcd >> 1;
  const int h = ((xcd & 1) << 3) | (ii >> 3);
  const int p = ii & 7;
  const int qtA = p, qtB = 15 - p;
  const int nstA = 2 * qtA + 2;
  const int ntot = nstA + 2 * qtB + 2;       // = 34

  const float FM = 16.0f;  // fixed softmax max (log2 domain); cancels in o/l

  bf16x8 qf[2][4];
  f32x4 o[2][8];
  float lrow[2];           // in-lane partial sums; reduced once at storeO

  auto loadQ = [&](int qrow0) {
#pragma unroll
    for (int m2 = 0; m2 < 2; ++m2)
#pragma unroll
      for (int c = 0; c < 4; ++c)
        qf[m2][c] = *(const bf16x8*)(Q + (size_t)(qrow0 + m2 * 16 + r) * Dm + h * Dh + c * 32 + g * 8);
  };
  auto resetAcc = [&]() {
#pragma unroll
    for (int m2 = 0; m2 < 2; ++m2) {
#pragma unroll
      for (int c = 0; c < 8; ++c) o[m2][c] = (f32x4)(0.f);
      lrow[m2] = 0.f;
    }
  };
  auto storeO = [&](int qrow0) {
#pragma unroll
    for (int m2 = 0; m2 < 2; ++m2) {
      float lt = lrow[m2];
      lt += __shfl_xor(lt, 16);
      lt += __shfl_xor(lt, 32);
      float linv[4];
#pragma unroll
      for (int j = 0; j < 4; ++j)
        linv[j] = __builtin_amdgcn_rcpf(__shfl(lt, 20 * g + j));
#pragma unroll
      for (int c = 0; c < 8; ++c)
#pragma unroll
        for (int j = 0; j < 4; ++j)
          O[(size_t)(qrow0 + m2 * 16 + 4 * g + j) * Dm + h * Dh + c * 16 + r] =
              cvt_bf(o[m2][c][j] * linv[j]);
    }
  };
  auto stageK = [&](int s0, char* dst) {
#pragma unroll
    for (int n = 0; n < 4; ++n) {
      const int L = n * 4096 + tid * 16;
      const int row = L >> 8;
      const int colb = (L & 255) ^ ((row & 7) << 4);
      gl2lds16((const char*)Kb + (size_t)(s0 + row) * (KVSTR * 2) + colb, dst + L);
    }
  };
  auto stageV = [&](int s0, char* dst) {
#pragma unroll
    for (int n = 0; n < 4; ++n) {
      const int L = n * 4096 + tid * 16;
      const int row = L >> 7;
      const int colb = (L & 127) ^ ((row & 7) << 4);
      gl2lds16((const char*)VT + ((size_t)row * BT + s0) * 2 + colb, dst + L);
    }
  };

  int qt = qtA;
  int qrow0 = b * Tn + qt * 128 + wq * 32;
  int qmin = qt * 128 + wq * 32;
  loadQ(qrow0);
  resetAcc();
  stageK(b * Tn, smem);
  stageV(b * Tn, smem + 32768);

  int cur = 0;
  for (int t = 0; t < ntot; ++t) {
    VMCNT(0);    // tile t's K+V landed (issued one full tile of compute ago)
    BARRIER();   // all waves' parts visible; buffers cur^1 dead

    if (t == nstA) {  // switch to second q-tile
      storeO(qrow0);
      qt = qtB;
      qrow0 = b * Tn + qt * 128 + wq * 32;
      qmin = qt * 128 + wq * 32;
      loadQ(qrow0);
      resetAcc();
    }
    const int st = (t < nstA) ? t : t - nstA;

    // issue tile t+1's loads into the other buffers
    {
      const int t1 = t + 1;
      const int st1 = (t1 >= ntot) ? 0 : ((t1 < nstA) ? t1 : t1 - nstA);
      stageK(b * Tn + st1 * 64, smem + ((cur ^ 1) << 14));
      stageV(b * Tn + st1 * 64, smem + 32768 + ((cur ^ 1) << 14));
    }

    const bool fullmask = (st * 64 >= qmin + 32); // wave-uniform
    if (!fullmask) {
      const char* Kc = smem + (cur << 14);
      const char* Vb = smem + 32768 + (cur << 14);
      f32x4 sf[2][4];
      __builtin_amdgcn_s_setprio(1);
#pragma unroll
      for (int n = 0; n < 4; ++n) {
        f32x4 sa = (f32x4)(0.f), sb = (f32x4)(0.f);
#pragma unroll
        for (int c = 0; c < 4; ++c) {
          const int row = n * 16 + r;
          bf16x8 kf = *(const bf16x8*)(Kc + row * 256 + ((c * 64 + g * 16) ^ ((row & 7) << 4)));
          sa = __builtin_amdgcn_mfma_f32_16x16x32_bf16(kf, qf[0][c], sa, 0, 0, 0);
          sb = __builtin_amdgcn_mfma_f32_16x16x32_bf16(kf, qf[1][c], sb, 0, 0, 0);
        }
        sf[0][n] = sa; sf[1][n] = sb;
      }
      __builtin_amdgcn_s_setprio(0);
      // causal mask: key = st*64 + n*16 + 4g + j ; q = qmin + m2*16 + r
      if (st * 64 + 63 > qmin) {
#pragma unroll
        for (int m2 = 0; m2 < 2; ++m2) {
          const int q = qmin + m2 * 16 + r;
#pragma unroll
          for (int n = 0; n < 4; ++n)
#pragma unroll
            for (int j = 0; j < 4; ++j) {
              const int key = st * 64 + n * 16 + 4 * g + j;
              if (key > q) sf[m2][n][j] = -1e30f;
            }
        }
      }
      // fixed-max exp2 + in-lane pack to PV A-frags (sigma order) + l-sum
      u32x4 pau[2][2];
#pragma unroll
      for (int m2 = 0; m2 < 2; ++m2) {
#pragma unroll
        for (int n = 0; n < 4; ++n) {
          const float p0 = __builtin_amdgcn_exp2f(sf[m2][n][0] - FM);
          const float p1 = __builtin_amdgcn_exp2f(sf[m2][n][1] - FM);
          const float p2 = __builtin_amdgcn_exp2f(sf[m2][n][2] - FM);
          const float p3 = __builtin_amdgcn_exp2f(sf[m2][n][3] - FM);
          lrow[m2] += (p0 + p1) + (p2 + p3);
          pau[m2][n >> 1][(n & 1) * 2]     = cvt_pk_bf16(p0, p1);
          pau[m2][n >> 1][(n & 1) * 2 + 1] = cvt_pk_bf16(p2, p3);
        }
      }

      // PV (conflict-free b128, sigma matches pau packing)
      __builtin_amdgcn_s_setprio(1);
#pragma unroll
      for (int kk = 0; kk < 2; ++kk) {
        if (st * 64 + kk * 32 >= qmin + 32) continue;
        const bf16x8 pa0 = __builtin_bit_cast(bf16x8, pau[0][kk]);
        const bf16x8 pa1 = __builtin_bit_cast(bf16x8, pau[1][kk]);
#pragma unroll
        for (int c = 0; c < 8; ++c) {
          const int row = c * 16 + r;
          const bf16x8 vb = *(const bf16x8*)(Vb + row * 128 + ((kk * 64 + g * 16) ^ ((row & 7) << 4)));
          o[0][c] = __builtin_amdgcn_mfma_f32_16x16x32_bf16(pa0, vb, o[0][c], 0, 0, 0);
          o[1][c] = __builtin_amdgcn_mfma_f32_16x16x32_bf16(pa1, vb, o[1][c], 0, 0, 0);
        }
      }
      __builtin_amdgcn_s_setprio(0);
    }
    cur ^= 1;
  }
  storeO(qrow0);
}

// ---------------- host launch ----------------
extern "C" void kernel_launch(void* const* d_in, const int* in_sizes, int n_in,
                              void* d_out, int out_size, void* d_ws, size_t ws_size,
                              hipStream_t stream) {
  const float* x  = (const float*)d_in[0];
  // d_in[1] = mask: unused (exactly causal triu(-inf), applied analytically)
  const float* Wq = (const float*)d_in[2];
  const float* bq = (const float*)d_in[3];
  const float* Wk = (const float*)d_in[4];
  const float* bk = (const float*)d_in[5];
  const float* Wv = (const float*)d_in[6];
  const float* bv = (const float*)d_in[7];
  const float* Wo = (const float*)d_in[8];
  const float* bo = (const float*)d_in[9];
  float* out = (float*)d_out;

  char* ws = (char*)d_ws;
  size_t off = 0;
  auto alloc = [&](size_t bytes) {
    char* p = ws + off;
    off += (bytes + 255) & ~(size_t)255;
    return p;
  };
  u16* xb   = (u16*)alloc((size_t)BT * Dm * 2);
  u16* Qb   = (u16*)alloc((size_t)BT * Dm * 2);
  u16* KVb  = (u16*)alloc((size_t)BT * KVSTR * 2);   // [token][K(128)|V(128)]
  u16* VTb  = (u16*)alloc((size_t)BT * Dh * 2);
  u16* Wqt  = (u16*)alloc((size_t)Dm * Dm * 2);
  u16* Wkvt = (u16*)alloc((size_t)Dm * KVSTR * 2);   // [K^T rows | V^T rows]
  u16* Wot  = (u16*)alloc((size_t)Dm * Dm * 2);
  u16* Ob   = xb;            // x_bf16 dead after projections
  float* Pkv = (float*)Qb;   // Qb (32MB) = exactly 4 f32 partial slices

  hipFuncSetAttribute(reinterpret_cast<const void*>(&k_gemm256<u16>),
                      hipFuncAttributeMaxDynamicSharedMemorySize, 131072);
  hipFuncSetAttribute(reinterpret_cast<const void*>(&k_gemm256<float>),
                      hipFuncAttributeMaxDynamicSharedMemorySize, 131072);

  dim3 tb(32, 8);
  // fused prep: z=0 cast x; z=1..4 transpose Wq/Wo/Wk/Wv
  k_prep<<<dim3(64, 64, 5), tb, 0, stream>>>(x, xb, Wq, Wqt, Wo, Wot, Wk, Wv, Wkvt);

  // KV projection: split-K=4 partials into Qb scratch, then reduce (+bias)
  k_gemm_kv<<<dim3(BT / 128, KVSTR / 128, 4), 256, 0, stream>>>(xb, Wkvt, Pkv, BT, KVSTR, Dm);
  k_kv_reduce<<<BT * KVSTR / 4 / 256, 256, 0, stream>>>(Pkv, bk, bv, KVb);

  // Q pre-scaled by log2(e)/sqrt(Dh) in the GEMM epilogue (overwrites Pkv)
  k_gemm256<u16><<<(BT / 256) * (Dm / 256), 512, 131072, stream>>>(xb, Wqt, bq, Qb, BT, Dm, Dm, CL2);
  k_transpose_v<<<dim3(Dh / 32, BT / 32), tb, 0, stream>>>(KVb + Dh, KVSTR, VTb, BT, Dh);

  k_attn<<<512, 256, 0, stream>>>(Qb, KVb, VTb, Ob);

  k_gemm256<float><<<(BT / 256) * (Dm / 256), 512, 131072, stream>>>(Ob, Wot, bo, out, BT, Dm, Dm, 1.0f);
}

// Round 16
// 262.600 us; speedup vs baseline: 1.0203x; 1.0203x over previous
//
#include <hip/hip_runtime.h>
#include <hip/hip_bf16.h>
#include <stdint.h>

#define DEV __device__ __forceinline__

typedef unsigned short u16;
typedef unsigned int u32;
typedef __bf16 bf16x8 __attribute__((ext_vector_type(8)));
typedef float f32x4 __attribute__((ext_vector_type(4)));
typedef u16 u16x4 __attribute__((ext_vector_type(4)));
typedef u32 u32x4 __attribute__((ext_vector_type(4)));

typedef __attribute__((address_space(1))) u32 u32_as1;
typedef __attribute__((address_space(3))) u32 u32_as3;

static constexpr int Bn = 4, Tn = 2048, Dm = 2048, Hn = 16, Dh = 128;
static constexpr int BT = Bn * Tn; // 8192
static constexpr int KVSTR = 256;  // fused K|V row stride (elements)
static constexpr float CL2 = 0.1275174147f; // log2(e)/sqrt(128)

#define VMCNT(n) asm volatile("s_waitcnt vmcnt(" #n ")" ::: "memory")
#define BARRIER() __builtin_amdgcn_s_barrier()

DEV u16 f2bf(float f) {
  u32 u = __builtin_bit_cast(u32, f);
  u += 0x7fffu + ((u >> 16) & 1u);   // RNE
  return (u16)(u >> 16);
}
DEV u16 cvt_bf(float f) { return __builtin_bit_cast(u16, (__bf16)f); }
DEV u32 cvt_pk_bf16(float lo, float hi) {   // u32 = {lo_bf16, hi_bf16<<16}
  u32 r;
  asm("v_cvt_pk_bf16_f32 %0, %1, %2" : "=v"(r) : "v"(lo), "v"(hi));
  return r;
}

// async 16B global->LDS; LDS dest is wave-linear (base + lane*16), so the
// XOR swizzle is applied on the GLOBAL source side (rule #21).
DEV void gl2lds16(const void* g, void* l) {
  __builtin_amdgcn_global_load_lds((u32_as1*)(uintptr_t)g,
                                   (u32_as3*)(u32)(uintptr_t)l, 16, 0, 0);
}

// ---------------- fused prep: cast x (z=0) + 4 weight transposes (z=1..4) ----
__global__ __launch_bounds__(256) void k_prep(const float* __restrict__ x,
                                              u16* __restrict__ xb,
                                              const float* __restrict__ Wq,
                                              u16* __restrict__ Wqt,
                                              const float* __restrict__ Wo,
                                              u16* __restrict__ Wot,
                                              const float* __restrict__ Wk,
                                              const float* __restrict__ Wv,
                                              u16* __restrict__ Wkvt) {
  const int z = blockIdx.z;
  const int xx = threadIdx.x, yy = threadIdx.y; // (32,8)
  if (z == 0) {  // cast f32 -> bf16 x4: 4096 blocks x 1024 groups (exact)
    const int tid = yy * 32 + xx;
    int i = (blockIdx.y * 64 + blockIdx.x) * 1024 + tid;
#pragma unroll
    for (int k = 0; k < 4; ++k, i += 256) {
      f32x4 v = ((const f32x4*)x)[i];
      u16x4 o;
      o.x = f2bf(v.x); o.y = f2bf(v.y); o.z = f2bf(v.z); o.w = f2bf(v.w);
      ((u16x4*)xb)[i] = o;
    }
    return;
  }
  const float* in; u16* out; int R, C;
  if (z == 1)      { in = Wq; out = Wqt; R = Dm; C = Dm; }
  else if (z == 2) { in = Wo; out = Wot; R = Dm; C = Dm; }
  else if (z == 3) { in = Wk; out = Wkvt; R = Dm; C = Dh; }
  else             { in = Wv; out = Wkvt + (size_t)Dh * Dm; R = Dm; C = Dh; }
  if (blockIdx.x * 32 >= C) return;  // block-uniform early out (Dh tensors)
  __shared__ float t[32][33];
  const int r0 = blockIdx.y * 32, c0 = blockIdx.x * 32;
#pragma unroll
  for (int i = 0; i < 4; ++i)
    t[yy + i * 8][xx] = in[(size_t)(r0 + yy + i * 8) * C + c0 + xx];
  __syncthreads();
#pragma unroll
  for (int i = 0; i < 4; ++i)
    out[(size_t)(c0 + yy + i * 8) * R + r0 + xx] = f2bf(t[xx][yy + i * 8]);
}

// ---- transpose bf16 in[R][inStride] (window C) -> out[C][R], with the PV
// kv-permutation sigma applied within each 32-token column group:
// out[d][base + x] = in[base + sigma(x)][d], sigma(8g+i)=16*(i>>2)+4g+(i&3).
__global__ __launch_bounds__(256) void k_transpose_v(const u16* __restrict__ in,
                                                     int inStride,
                                                     u16* __restrict__ out,
                                                     int R, int C) {
  __shared__ u16 t[32][34];
  const int r0 = blockIdx.y * 32, c0 = blockIdx.x * 32;
  const int x = threadIdx.x, y = threadIdx.y;
#pragma unroll
  for (int i = 0; i < 4; ++i)
    t[y + i * 8][x] = in[(size_t)(r0 + y + i * 8) * inStride + c0 + x];
  __syncthreads();
  const int sx = (((x & 7) >> 2) << 4) | (((x >> 3) & 3) << 2) | (x & 3);
#pragma unroll
  for (int i = 0; i < 4; ++i)
    out[(size_t)(c0 + y + i * 8) * R + r0 + x] = t[sx][y + i * 8];
}

// ---------------- KV projection, split-K=4: partial f32 (no bias) ----------------
__global__ __launch_bounds__(256) void k_gemm_kv(const u16* __restrict__ A,
                                                 const u16* __restrict__ Bt,
                                                 float* __restrict__ P,
                                                 int M, int N, int K) {
  __shared__ __align__(128) char smem[32768];
  char* As = smem;
  char* Bs = smem + 16384;
  const int tid = threadIdx.x;
  const int wid = tid >> 6, lane = tid & 63;
  const int g = lane >> 4, r = lane & 15;
  const int wr = wid >> 1, wc = wid & 1;
  const int m0 = blockIdx.x * 128, n0 = blockIdx.y * 128;
  const int kbase = blockIdx.z * 512;
  P += (size_t)blockIdx.z * M * N;

  f32x4 acc[4][4];
#pragma unroll
  for (int m = 0; m < 4; ++m)
#pragma unroll
    for (int n = 0; n < 4; ++n) acc[m][n] = (f32x4)(0.f);

  for (int k0 = kbase; k0 < kbase + 512; k0 += 64) {
#pragma unroll
    for (int n = 0; n < 4; ++n) {
      const int L = n * 4096 + tid * 16;
      const int row = L >> 7;
      const int colb = (L & 127) ^ ((row & 7) << 4);
      gl2lds16((const char*)A + ((size_t)(m0 + row) * K + k0) * 2 + colb, As + L);
      gl2lds16((const char*)Bt + ((size_t)(n0 + row) * K + k0) * 2 + colb, Bs + L);
    }
    __syncthreads();
#pragma unroll
    for (int kk = 0; kk < 2; ++kk) {
      bf16x8 a[4], b[4];
#pragma unroll
      for (int m = 0; m < 4; ++m) {
        const int row = wr * 64 + m * 16 + r;
        a[m] = *(const bf16x8*)(As + row * 128 + ((kk * 64 + g * 16) ^ ((row & 7) << 4)));
      }
#pragma unroll
      for (int n = 0; n < 4; ++n) {
        const int row = wc * 64 + n * 16 + r;
        b[n] = *(const bf16x8*)(Bs + row * 128 + ((kk * 64 + g * 16) ^ ((row & 7) << 4)));
      }
#pragma unroll
      for (int m = 0; m < 4; ++m)
#pragma unroll
        for (int n = 0; n < 4; ++n)
          acc[m][n] = __builtin_amdgcn_mfma_f32_16x16x32_bf16(a[m], b[n], acc[m][n], 0, 0, 0);
    }
    __syncthreads();
  }

#pragma unroll
  for (int n = 0; n < 4; ++n) {
    const int col = n0 + wc * 64 + n * 16 + r;
#pragma unroll
    for (int m = 0; m < 4; ++m)
#pragma unroll
      for (int j = 0; j < 4; ++j) {
        const int grow = m0 + wr * 64 + m * 16 + 4 * g + j;
        P[(size_t)grow * N + col] = acc[m][n][j];
      }
  }
}

// ---------------- KV reduce: sum 4 partials + bias -> bf16 KV ----------------
__global__ __launch_bounds__(256) void k_kv_reduce(const float* __restrict__ P,
                                                   const float* __restrict__ bk,
                                                   const float* __restrict__ bv,
                                                   u16* __restrict__ KV) {
  const int i = blockIdx.x * 256 + threadIdx.x;     // f32x4 group index
  const size_t S = (size_t)BT * KVSTR / 4;          // groups per slice
  f32x4 s0 = ((const f32x4*)P)[i];
  f32x4 s1 = ((const f32x4*)P)[i + S];
  f32x4 s2 = ((const f32x4*)P)[i + 2 * S];
  f32x4 s3 = ((const f32x4*)P)[i + 3 * S];
  const int col = (i * 4) & (KVSTR - 1);
  u16x4 o;
#pragma unroll
  for (int j = 0; j < 4; ++j) {
    const int c = col + j;
    const float b = (c < Dh) ? bk[c] : bv[c - Dh];
    o[j] = cvt_bf((s0[j] + s1[j]) + (s2[j] + s3[j]) + b);
  }
  ((u16x4*)KV)[i] = o;
}

// ---------------- GEMM 256x256, 8-wave, 4-phase/K-tile, counted vmcnt ----------
// t+2 staging spread to earliest region-free points (all wave-uniform):
//  A chunks of qm0-region waves (wid&3<2) + B chunks of even-segment waves
//  (wid&1==0) issue after p1's 1st barrier; B odd-segment after p2's; A qm1
//  after p3's. Per-wave outstanding at p4 = 16 -> VMCNT(8) drains exactly
//  t+1's 8 oldest (vmcnt retires in issue order, m135).
template <typename OutT>
__global__ __launch_bounds__(512, 2) void k_gemm256(const u16* __restrict__ A,
                                                    const u16* __restrict__ Bt,
                                                    const float* __restrict__ bias,
                                                    OutT* __restrict__ C,
                                                    int M, int N, int K,
                                                    float oscale) {
  extern __shared__ char smem[];
  const int tid = threadIdx.x;
  const int wid = tid >> 6, lane = tid & 63;
  const int g = lane >> 4, r = lane & 15;
  const int wm = wid >> 2, wn = wid & 3;

  const int nbn = N >> 8;
  const int cpx = gridDim.x >> 3;
  const int linear = (blockIdx.x & 7) * cpx + (blockIdx.x >> 3);
  const int m0 = (linear / nbn) << 8;
  const int n0 = (linear % nbn) << 8;

  const bool aEarly = (wid & 3) < 2;   // this wave's A chunks lie in qm0 rows
  const bool bEarly = (wid & 1) == 0;  // this wave's B chunks lie in qn0 rows

  const int rowInCh = lane >> 3;
  const int colb = ((lane & 7) << 4) ^ (rowInCh << 4);
  const char* srcA0; const char* srcA1; const char* srcA2; const char* srcA3;
  const char* srcB0; const char* srcB1; const char* srcB2; const char* srcB3;
  int ldsA[4], ldsB[4];
  {
    const int wnh = (wid >> 1) & 1;
    const int cbb = ((wid >> 2) << 1) | (wid & 1);
    const char* sa[4]; const char* sb[4];
#pragma unroll
    for (int i = 0; i < 4; ++i) {
      const int chA = ((wid & 3) << 2) + i;
      const int lrA = (wm << 7) + (chA << 3) + rowInCh;
      sa[i] = (const char*)A + ((size_t)(m0 + lrA) * K) * 2 + colb;
      ldsA[i] = ((wm << 7) + (chA << 3)) * 128 + lane * 16;
      const int chB = (cbb << 2) + i;
      const int lrB = (wnh << 7) + (chB << 3) + rowInCh;
      sb[i] = (const char*)Bt + ((size_t)(n0 + lrB) * K) * 2 + colb;
      ldsB[i] = 32768 + ((wnh << 7) + (chB << 3)) * 128 + lane * 16;
    }
    srcA0 = sa[0]; srcA1 = sa[1]; srcA2 = sa[2]; srcA3 = sa[3];
    srcB0 = sb[0]; srcB1 = sb[1]; srcB2 = sb[2]; srcB3 = sb[3];
  }

  auto stageA = [&](int t, int b) {
    const size_t ko = (size_t)t * 128;
    char* base = smem + (b << 16);
    gl2lds16(srcA0 + ko, base + ldsA[0]);
    gl2lds16(srcA1 + ko, base + ldsA[1]);
    gl2lds16(srcA2 + ko, base + ldsA[2]);
    gl2lds16(srcA3 + ko, base + ldsA[3]);
  };
  auto stageB = [&](int t, int b) {
    const size_t ko = (size_t)t * 128;
    char* base = smem + (b << 16);
    gl2lds16(srcB0 + ko, base + ldsB[0]);
    gl2lds16(srcB1 + ko, base + ldsB[1]);
    gl2lds16(srcB2 + ko, base + ldsB[2]);
    gl2lds16(srcB3 + ko, base + ldsB[3]);
  };

  f32x4 acc[8][4];
#pragma unroll
  for (int m = 0; m < 8; ++m)
#pragma unroll
    for (int n = 0; n < 4; ++n) acc[m][n] = (f32x4)(0.f);

  auto readA = [&](const char* Ab, int qm, bf16x8 (&a)[8]) {
#pragma unroll
    for (int m = 0; m < 4; ++m) {
      const int row = (wm << 7) + ((qm * 4 + m) << 4) + r;
#pragma unroll
      for (int kk = 0; kk < 2; ++kk)
        a[m * 2 + kk] = *(const bf16x8*)(Ab + row * 128 + ((kk * 64 + g * 16) ^ ((row & 7) << 4)));
    }
  };
  auto readB = [&](const char* Bb, int qn, bf16x8 (&b)[4]) {
#pragma unroll
    for (int n = 0; n < 2; ++n) {
      const int row = (wn << 6) + ((qn * 2 + n) << 4) + r;
#pragma unroll
      for (int kk = 0; kk < 2; ++kk)
        b[n * 2 + kk] = *(const bf16x8*)(Bb + row * 128 + ((kk * 64 + g * 16) ^ ((row & 7) << 4)));
    }
  };
  auto mfmaQ = [&](const bf16x8 (&a)[8], const bf16x8 (&b)[4], int qm, int qn) {
    __builtin_amdgcn_s_setprio(1);
#pragma unroll
    for (int m = 0; m < 4; ++m)
#pragma unroll
      for (int n = 0; n < 2; ++n)
#pragma unroll
        for (int kk = 0; kk < 2; ++kk)
          acc[qm * 4 + m][qn * 2 + n] = __builtin_amdgcn_mfma_f32_16x16x32_bf16(
              a[m * 2 + kk], b[n * 2 + kk], acc[qm * 4 + m][qn * 2 + n], 0, 0, 0);
    __builtin_amdgcn_s_setprio(0);
  };

  const int NT = K >> 6;
  stageA(0, 0); stageB(0, 0);
  stageA(1, 1); stageB(1, 1);
  VMCNT(8);
  BARRIER();

  bf16x8 a0[8], a1[8], b0[4], b1[4];
  for (int t = 0; t < NT; ++t) {
    const char* Ab = smem + ((t & 1) << 16);
    const char* Bb = Ab + 32768;
    const bool pre = (t + 2 < NT);
    // phase 1
    readA(Ab, 0, a0);
    readB(Bb, 0, b0);
    BARRIER();
    if (pre) {
      if (aEarly) stageA(t + 2, t & 1);   // qm0 A-rows free after p1 barrier
      if (bEarly) stageB(t + 2, t & 1);   // qn0 B-rows free after p1 barrier
    }
    mfmaQ(a0, b0, 0, 0);
    BARRIER();
    // phase 2
    readB(Bb, 1, b1);
    BARRIER();
    if (pre && !bEarly) stageB(t + 2, t & 1);  // qn1 B-rows free after p2
    mfmaQ(a0, b1, 0, 1);
    BARRIER();
    // phase 3
    readA(Ab, 1, a1);
    BARRIER();
    if (pre && !aEarly) stageA(t + 2, t & 1);  // qm1 A-rows free after p3
    mfmaQ(a1, b1, 1, 1);
    BARRIER();
    // phase 4
    mfmaQ(a1, b0, 1, 0);
    if (pre) { VMCNT(8); } else { VMCNT(0); }
    BARRIER();
  }

#pragma unroll
  for (int n = 0; n < 4; ++n) {
    const int col = n0 + wn * 64 + n * 16 + r;
    const float bv = bias[col];
#pragma unroll
    for (int m = 0; m < 8; ++m) {
#pragma unroll
      for (int j = 0; j < 4; ++j) {
        const int grow = m0 + wm * 128 + m * 16 + 4 * g + j;
        const float v = (acc[m][n][j] + bv) * oscale;
        if constexpr (sizeof(OutT) == 2)
          ((u16*)C)[(size_t)grow * N + col] = cvt_bf(v);
        else
          ((float*)C)[(size_t)grow * N + col] = v;
      }
    }
  }
}

// ---------------- flash attention (MQA), causal, SWAPPED QK^T ----------------
// R13 best (83us): 512 uniform paired blocks, 4 waves x 32 q-rows, 2 blocks/CU,
// K+V dbuf, one VMCNT(0)+BARRIER per tile, FIXED-MAX softmax (FM=16).
__global__ __launch_bounds__(256, 2) void k_attn(const u16* __restrict__ Q,
                                                 const u16* __restrict__ Kb,
                                                 const u16* __restrict__ VT,
                                                 u16* __restrict__ O) {
  __shared__ __align__(1024) char smem[65536];
  // K dbuf: smem + (cur<<14)          (2 x 16KB, [64 kv][256B] swizzled)
  // V dbuf: smem + 32768 + (cur<<14)  (2 x 16KB, [128 d][128B kv] swz+perm)

  const int tid = threadIdx.x;
  const int wq = tid >> 6, lane = tid & 63;
  const int g = lane >> 4, r = lane & 15;

  const int bid = blockIdx.x;                // 512
  const int xcd = bid & 7, ii = bid >> 3;    // ii 0..63
  const int b = xcd >> 1;
  const int h = ((xcd & 1) << 3) | (ii >> 3);
  const int p = ii & 7;
  const int qtA = p, qtB = 15 - p;
  const int nstA = 2 * qtA + 2;
  const int ntot = nstA + 2 * qtB + 2;       // = 34

  const float FM = 16.0f;  // fixed softmax max (log2 domain); cancels in o/l

  bf16x8 qf[2][4];
  f32x4 o[2][8];
  float lrow[2];           // in-lane partial sums; reduced once at storeO

  auto loadQ = [&](int qrow0) {
#pragma unroll
    for (int m2 = 0; m2 < 2; ++m2)
#pragma unroll
      for (int c = 0; c < 4; ++c)
        qf[m2][c] = *(const bf16x8*)(Q + (size_t)(qrow0 + m2 * 16 + r) * Dm + h * Dh + c * 32 + g * 8);
  };
  auto resetAcc = [&]() {
#pragma unroll
    for (int m2 = 0; m2 < 2; ++m2) {
#pragma unroll
      for (int c = 0; c < 8; ++c) o[m2][c] = (f32x4)(0.f);
      lrow[m2] = 0.f;
    }
  };
  auto storeO = [&](int qrow0) {
#pragma unroll
    for (int m2 = 0; m2 < 2; ++m2) {
      float lt = lrow[m2];
      lt += __shfl_xor(lt, 16);
      lt += __shfl_xor(lt, 32);
      float linv[4];
#pragma unroll
      for (int j = 0; j < 4; ++j)
        linv[j] = __builtin_amdgcn_rcpf(__shfl(lt, 20 * g + j));
#pragma unroll
      for (int c = 0; c < 8; ++c)
#pragma unroll
        for (int j = 0; j < 4; ++j)
          O[(size_t)(qrow0 + m2 * 16 + 4 * g + j) * Dm + h * Dh + c * 16 + r] =
              cvt_bf(o[m2][c][j] * linv[j]);
    }
  };
  auto stageK = [&](int s0, char* dst) {
#pragma unroll
    for (int n = 0; n < 4; ++n) {
      const int L = n * 4096 + tid * 16;
      const int row = L >> 8;
      const int colb = (L & 255) ^ ((row & 7) << 4);
      gl2lds16((const char*)Kb + (size_t)(s0 + row) * (KVSTR * 2) + colb, dst + L);
    }
  };
  auto stageV = [&](int s0, char* dst) {
#pragma unroll
    for (int n = 0; n < 4; ++n) {
      const int L = n * 4096 + tid * 16;
      const int row = L >> 7;
      const int colb = (L & 127) ^ ((row & 7) << 4);
      gl2lds16((const char*)VT + ((size_t)row * BT + s0) * 2 + colb, dst + L);
    }
  };

  int qt = qtA;
  int qrow0 = b * Tn + qt * 128 + wq * 32;
  int qmin = qt * 128 + wq * 32;
  loadQ(qrow0);
  resetAcc();
  stageK(b * Tn, smem);
  stageV(b * Tn, smem + 32768);

  int cur = 0;
  for (int t = 0; t < ntot; ++t) {
    VMCNT(0);    // tile t's K+V landed (issued one full tile of compute ago)
    BARRIER();   // all waves' parts visible; buffers cur^1 dead

    if (t == nstA) {  // switch to second q-tile
      storeO(qrow0);
      qt = qtB;
      qrow0 = b * Tn + qt * 128 + wq * 32;
      qmin = qt * 128 + wq * 32;
      loadQ(qrow0);
      resetAcc();
    }
    const int st = (t < nstA) ? t : t - nstA;

    // issue tile t+1's loads into the other buffers
    {
      const int t1 = t + 1;
      const int st1 = (t1 >= ntot) ? 0 : ((t1 < nstA) ? t1 : t1 - nstA);
      stageK(b * Tn + st1 * 64, smem + ((cur ^ 1) << 14));
      stageV(b * Tn + st1 * 64, smem + 32768 + ((cur ^ 1) << 14));
    }

    const bool fullmask = (st * 64 >= qmin + 32); // wave-uniform
    if (!fullmask) {
      const char* Kc = smem + (cur << 14);
      const char* Vb = smem + 32768 + (cur << 14);
      f32x4 sf[2][4];
      __builtin_amdgcn_s_setprio(1);
#pragma unroll
      for (int n = 0; n < 4; ++n) {
        f32x4 sa = (f32x4)(0.f), sb = (f32x4)(0.f);
#pragma unroll
        for (int c = 0; c < 4; ++c) {
          const int row = n * 16 + r;
          bf16x8 kf = *(const bf16x8*)(Kc + row * 256 + ((c * 64 + g * 16) ^ ((row & 7) << 4)));
          sa = __builtin_amdgcn_mfma_f32_16x16x32_bf16(kf, qf[0][c], sa, 0, 0, 0);
          sb = __builtin_amdgcn_mfma_f32_16x16x32_bf16(kf, qf[1][c], sb, 0, 0, 0);
        }
        sf[0][n] = sa; sf[1][n] = sb;
      }
      __builtin_amdgcn_s_setprio(0);
      // causal mask: key = st*64 + n*16 + 4g + j ; q = qmin + m2*16 + r
      if (st * 64 + 63 > qmin) {
#pragma unroll
        for (int m2 = 0; m2 < 2; ++m2) {
          const int q = qmin + m2 * 16 + r;
#pragma unroll
          for (int n = 0; n < 4; ++n)
#pragma unroll
            for (int j = 0; j < 4; ++j) {
              const int key = st * 64 + n * 16 + 4 * g + j;
              if (key > q) sf[m2][n][j] = -1e30f;
            }
        }
      }
      // fixed-max exp2 + in-lane pack to PV A-frags (sigma order) + l-sum
      u32x4 pau[2][2];
#pragma unroll
      for (int m2 = 0; m2 < 2; ++m2) {
#pragma unroll
        for (int n = 0; n < 4; ++n) {
          const float p0 = __builtin_amdgcn_exp2f(sf[m2][n][0] - FM);
          const float p1 = __builtin_amdgcn_exp2f(sf[m2][n][1] - FM);
          const float p2 = __builtin_amdgcn_exp2f(sf[m2][n][2] - FM);
          const float p3 = __builtin_amdgcn_exp2f(sf[m2][n][3] - FM);
          lrow[m2] += (p0 + p1) + (p2 + p3);
          pau[m2][n >> 1][(n & 1) * 2]     = cvt_pk_bf16(p0, p1);
          pau[m2][n >> 1][(n & 1) * 2 + 1] = cvt_pk_bf16(p2, p3);
        }
      }

      // PV (conflict-free b128, sigma matches pau packing)
      __builtin_amdgcn_s_setprio(1);
#pragma unroll
      for (int kk = 0; kk < 2; ++kk) {
        if (st * 64 + kk * 32 >= qmin + 32) continue;
        const bf16x8 pa0 = __builtin_bit_cast(bf16x8, pau[0][kk]);
        const bf16x8 pa1 = __builtin_bit_cast(bf16x8, pau[1][kk]);
#pragma unroll
        for (int c = 0; c < 8; ++c) {
          const int row = c * 16 + r;
          const bf16x8 vb = *(const bf16x8*)(Vb + row * 128 + ((kk * 64 + g * 16) ^ ((row & 7) << 4)));
          o[0][c] = __builtin_amdgcn_mfma_f32_16x16x32_bf16(pa0, vb, o[0][c], 0, 0, 0);
          o[1][c] = __builtin_amdgcn_mfma_f32_16x16x32_bf16(pa1, vb, o[1][c], 0, 0, 0);
        }
      }
      __builtin_amdgcn_s_setprio(0);
    }
    cur ^= 1;
  }
  storeO(qrow0);
}

// ---------------- host launch ----------------
extern "C" void kernel_launch(void* const* d_in, const int* in_sizes, int n_in,
                              void* d_out, int out_size, void* d_ws, size_t ws_size,
                              hipStream_t stream) {
  const float* x  = (const float*)d_in[0];
  // d_in[1] = mask: unused (exactly causal triu(-inf), applied analytically)
  const float* Wq = (const float*)d_in[2];
  const float* bq = (const float*)d_in[3];
  const float* Wk = (const float*)d_in[4];
  const float* bk = (const float*)d_in[5];
  const float* Wv = (const float*)d_in[6];
  const float* bv = (const float*)d_in[7];
  const float* Wo = (const float*)d_in[8];
  const float* bo = (const float*)d_in[9];
  float* out = (float*)d_out;

  char* ws = (char*)d_ws;
  size_t off = 0;
  auto alloc = [&](size_t bytes) {
    char* p = ws + off;
    off += (bytes + 255) & ~(size_t)255;
    return p;
  };
  u16* xb   = (u16*)alloc((size_t)BT * Dm * 2);
  u16* Qb   = (u16*)alloc((size_t)BT * Dm * 2);
  u16* KVb  = (u16*)alloc((size_t)BT * KVSTR * 2);   // [token][K(128)|V(128)]
  u16* VTb  = (u16*)alloc((size_t)BT * Dh * 2);
  u16* Wqt  = (u16*)alloc((size_t)Dm * Dm * 2);
  u16* Wkvt = (u16*)alloc((size_t)Dm * KVSTR * 2);   // [K^T rows | V^T rows]
  u16* Wot  = (u16*)alloc((size_t)Dm * Dm * 2);
  u16* Ob   = xb;            // x_bf16 dead after projections
  float* Pkv = (float*)Qb;   // Qb (32MB) = exactly 4 f32 partial slices

  hipFuncSetAttribute(reinterpret_cast<const void*>(&k_gemm256<u16>),
                      hipFuncAttributeMaxDynamicSharedMemorySize, 131072);
  hipFuncSetAttribute(reinterpret_cast<const void*>(&k_gemm256<float>),
                      hipFuncAttributeMaxDynamicSharedMemorySize, 131072);

  dim3 tb(32, 8);
  // fused prep: z=0 cast x; z=1..4 transpose Wq/Wo/Wk/Wv
  k_prep<<<dim3(64, 64, 5), tb, 0, stream>>>(x, xb, Wq, Wqt, Wo, Wot, Wk, Wv, Wkvt);

  // KV projection: split-K=4 partials into Qb scratch, then reduce (+bias)
  k_gemm_kv<<<dim3(BT / 128, KVSTR / 128, 4), 256, 0, stream>>>(xb, Wkvt, Pkv, BT, KVSTR, Dm);
  k_kv_reduce<<<BT * KVSTR / 4 / 256, 256, 0, stream>>>(Pkv, bk, bv, KVb);

  // Q pre-scaled by log2(e)/sqrt(Dh) in the GEMM epilogue (overwrites Pkv)
  k_gemm256<u16><<<(BT / 256) * (Dm / 256), 512, 131072, stream>>>(xb, Wqt, bq, Qb, BT, Dm, Dm, CL2);
  k_transpose_v<<<dim3(Dh / 32, BT / 32), tb, 0, stream>>>(KVb + Dh, KVSTR, VTb, BT, Dh);

  k_attn<<<512, 256, 0, stream>>>(Qb, KVb, VTb, Ob);

  k_gemm256<float><<<(BT / 256) * (Dm / 256), 512, 131072, stream>>>(Ob, Wot, bo, out, BT, Dm, Dm, 1.0f);
}